// Round 3
// baseline (35914.371 us; speedup 1.0000x reference)
//
#include <hip/hip_runtime.h>
#include <math.h>

#define SEQ 1000
#define IND 76
// 2-pad at index 50 so 50-element chunks start 16B-aligned (0 and 52)
#define PF(i) ((i) + (((i) >= 50) ? 2 : 0))

__device__ __forceinline__ float sigf(float v) { return 1.0f / (1.0f + expf(-v)); }

// 1024 threads. Roles:
//  t<800:   stage2 slot: r=t>>3 (liquid row 0..99), aa=(t>>2)&1 (0=Wm/tauM,1=Wa/tauA),
//           c3=t&3 (chunk): c3<2 -> late cols [50c3,+50) over dx; c3>=2 -> early cols
//           [100+50(c3-2),+50) over lm/lb. Weights wreg[0..49].
//           Owner (t&7)==0 holds liquid state lm/lb/ls for row r.
//  t<400:   + L2 row t (38 masked cols) in wreg[50..87]; n2=t>>2, gather at c3==0 owns m2/s2.
//  t in[400,800): + dx slot rd=(t>>2)-100, same c3 split, weights wreg[50..99].
//  t in[800,1000): L1 row slot: n1=(t-800)>>2, k=t&3, row 4*n1+k, wreg[0..31];
//           k==0 owns m1/s1; pipelined one step ahead.
//  t in[1000,1019): x prefetch (3 phases deep); t in[1000,1008): r2 reduce;
//  t in{1020,1021}: readout md owner.
__global__ __launch_bounds__(1024, 4) void dhsnn_fwd(
    const float* __restrict__ x,
    const float* __restrict__ W1, const float* __restrict__ b1,
    const float* __restrict__ tau_m1, const float* __restrict__ tau_n1,
    const float* __restrict__ W2, const float* __restrict__ b2,
    const float* __restrict__ tau_m2, const float* __restrict__ tau_n2,
    const float* __restrict__ Wxp, const float* __restrict__ bxp,
    const float* __restrict__ Wm, const float* __restrict__ bm,
    const float* __restrict__ Wa, const float* __restrict__ ba,
    const float* __restrict__ Wd, const float* __restrict__ bd,
    const float* __restrict__ tau_md,
    float* __restrict__ out)
{
    const int t   = (int)threadIdx.x;
    const int blk = (int)blockIdx.x;

    __shared__ __align__(16) float kin1P[128];    // [0..75] xt(j+1), [76..125] s1(j), [126..127]=0
    __shared__ __align__(16) float kin2P[4][40];  // branch windows of [s1(50), s2(100)], 2-pad each
    __shared__ __align__(16) float s2P[104];      // PF-padded 100-vectors
    __shared__ __align__(16) float dxP[104];
    __shared__ __align__(16) float lsP[104];
    __shared__ __align__(16) float lmP[104];
    __shared__ __align__(16) float lbP[104];
    __shared__ __align__(16) float rpart[200];
    __shared__ __align__(16) float r2[8];
    __shared__ float alpha2S[100], bmS[100], baS[100], bxS[100], wdS[200];

    // ---- zero LDS ----
    for (int i = t; i < 128; i += 1024) kin1P[i] = 0.f;
    for (int i = t; i < 160; i += 1024) (&kin2P[0][0])[i] = 0.f;
    for (int i = t; i < 104; i += 1024) { s2P[i]=0.f; dxP[i]=0.f; lsP[i]=0.f; lmP[i]=0.f; lbP[i]=0.f; }
    for (int i = t; i < 200; i += 1024) rpart[i] = 0.f;
    if (t < 8) r2[t] = 0.f;
    // scalar params to LDS
    if (t < 100) { alpha2S[t] = sigf(tau_m2[t]); bmS[t] = bm[t]; baS[t] = ba[t]; bxS[t] = bxp[t]; }
    if (t < 200) wdS[t] = Wd[(t < 100 ? 0 : 100) + (t % 100)];

    const int r     = t >> 3;
    const int aa    = (t >> 2) & 1;
    const int c3    = t & 3;
    const int lbase = (t & 63) & ~3;
    const int lb8   = (t & 63) & ~7;

    float wreg[100];
    #pragma unroll
    for (int i = 0; i < 100; ++i) wreg[i] = 0.f;

    // unioned persistent scalars (role-dependent meaning)
    float rA=0.f, rB=0.f, rC=0.f, rD=0.f, rE=0.f, rF=0.f;
    float rG=0.f, rH=0.f, rI=0.f, rJ=0.f, rK=0.f;
    float4 xpO = make_float4(0.f,0.f,0.f,0.f);
    float4 xpN = make_float4(0.f,0.f,0.f,0.f);

    // ---- weight init ----
    if (t < 800) {
        const float* Wrow = (aa ? Wa : Wm) + r * 200;
        const int colb = (c3 < 2) ? (50 * c3) : (100 + 50 * (c3 - 2));
        #pragma unroll
        for (int u = 0; u < 50; ++u) wreg[u] = Wrow[colb + u];
        if ((t & 7) == 0) rJ = 1.6f;                 // lb init = b_j0
    }
    if (t < 400) {
        #pragma unroll
        for (int u = 0; u < 38; ++u) {
            const int gc = 38 * c3 + u;
            wreg[50 + u] = (gc < 150) ? W2[t * 150 + gc] : 0.f;
        }
        rD = b2[t];                 // b2 row
        rE = sigf(tau_n2[t]);       // beta2 row
    } else if (t < 800) {
        const int rd = (t >> 2) - 100;
        const int colb = (c3 < 2) ? (50 * c3) : (100 + 50 * (c3 - 2));
        #pragma unroll
        for (int u = 0; u < 50; ++u) wreg[50 + u] = Wxp[rd * 200 + colb + u];
    } else if (t < 1000) {
        const int l = t - 800, n1 = l >> 2, k = l & 3, row = 4 * n1 + k;
        #pragma unroll
        for (int u = 0; u < 32; ++u) {
            const int gc = 32 * k + u;
            wreg[u] = (gc < 126) ? W1[row * 126 + gc] : 0.f;
        }
        rD = b1[row];
        rE = sigf(tau_n1[row]);
        if (k == 0) rF = sigf(tau_m1[n1]);   // alpha1
    } else if (t == 1020 || t == 1021) {
        rF = sigf(tau_md[t - 1020]);         // alpha_d
        rG = bd[t - 1020];                   // bd
    }

    // L1 row step: proj over kin1P cols [32k,+32); d1 update; 4-lane gather -> m1/s1 at k==0
    auto l1_row = [&]() {
        const int k = t & 3;
        const float* ap = kin1P + 32 * k;
        float p0 = rD, p1 = 0.f, p2 = 0.f, p3 = 0.f;
        #pragma unroll
        for (int u4 = 0; u4 < 8; ++u4) {
            const float4 av = *reinterpret_cast<const float4*>(ap + 4 * u4);
            p0 = fmaf(wreg[4*u4+0], av.x, p0);
            p1 = fmaf(wreg[4*u4+1], av.y, p1);
            p2 = fmaf(wreg[4*u4+2], av.z, p2);
            p3 = fmaf(wreg[4*u4+3], av.w, p3);
        }
        const float proj = (p0 + p1) + (p2 + p3);
        rA = rE * rA + (1.f - rE) * proj;                       // d1
        const float d1 = __shfl(rA, lbase + 1, 64);
        const float d2 = __shfl(rA, lbase + 2, 64);
        const float d3 = __shfl(rA, lbase + 3, 64);
        if (k == 0) {
            const float sum = ((rA + d1) + d2) + d3;
            rB = rF * rB + (1.f - rF) * sum - rC;               // m1
            rC = (rB - 1.0f > 0.f) ? 1.f : 0.f;                 // s1
        }
    };

    __syncthreads();
    if (t < 100) lbP[PF(t)] = 1.6f;
    if (t >= 1000 && t < 1019) {    // xt(0)
        *reinterpret_cast<float4*>(&kin1P[4 * (t - 1000)]) =
            *reinterpret_cast<const float4*>(x + (size_t)blk * SEQ * IND + 4 * (t - 1000));
    }
    __syncthreads();
    if (t >= 800 && t < 1000) l1_row();   // step 0 (s1 part zero)
    __syncthreads();
    if (t >= 800 && t < 1000 && (t & 3) == 0) {   // s1(0) -> kin buffers
        const int n1 = (t - 800) >> 2;
        kin1P[76 + n1] = rC;
        const int w = (n1 >= 38) ? 1 : 0;
        kin2P[w][n1 - 38 * w] = rC;
    }
    if (t >= 1000 && t < 1019) {    // xt(1)
        *reinterpret_cast<float4*>(&kin1P[4 * (t - 1000)]) =
            *reinterpret_cast<const float4*>(x + ((size_t)blk * SEQ + 1) * IND + 4 * (t - 1000));
        // preload xt(2) into the write-pipeline register
        xpO = *reinterpret_cast<const float4*>(x + ((size_t)blk * SEQ + 2) * IND + 4 * (t - 1000));
    }
    __syncthreads();

    for (int j = 0; j < SEQ; ++j) {
        // ===== B0: L2(j)+m2/s2; stage2-early(lm/lb); dx-early(ls); rpart; L1(j+1); prefetch issue =====
        if (t < 800) {
            if (t < 400) {
                const float* kw = kin2P[c3];
                float a0=0.f, a1=0.f, a2=0.f, a3=0.f;
                #pragma unroll
                for (int cc = 0; cc < 9; ++cc) {
                    const float4 av = *reinterpret_cast<const float4*>(kw + 4 * cc);
                    a0 = fmaf(wreg[50 + 4*cc + 0], av.x, a0);
                    a1 = fmaf(wreg[50 + 4*cc + 1], av.y, a1);
                    a2 = fmaf(wreg[50 + 4*cc + 2], av.z, a2);
                    a3 = fmaf(wreg[50 + 4*cc + 3], av.w, a3);
                }
                a0 = fmaf(wreg[86], kw[36], a0);
                a1 = fmaf(wreg[87], kw[37], a1);
                const float proj = rD + ((a0 + a1) + (a2 + a3));
                rA = rE * rA + (1.f - rE) * proj;                 // d2
                const float d1 = __shfl(rA, lbase + 1, 64);
                const float d2 = __shfl(rA, lbase + 2, 64);
                const float d3 = __shfl(rA, lbase + 3, 64);
                if (c3 == 0) {
                    const int n2 = t >> 2;
                    const float al = alpha2S[n2];
                    const float sum = ((rA + d1) + d2) + d3;
                    rB = al * rB + (1.f - al) * sum - rC;         // m2
                    rC = (rB - 1.0f > 0.f) ? 1.f : 0.f;           // s2
                    s2P[PF(n2)] = rC;
                }
            }
            if (c3 >= 2) {
                {   // stage2-early over lm (aa=0) / lb (aa=1)
                    const float* ap = (aa ? lbP : lmP) + ((c3 == 3) ? 52 : 0);
                    float e0=0.f, e1=0.f, e2=0.f, e3=0.f;
                    #pragma unroll
                    for (int u4 = 0; u4 < 12; ++u4) {
                        const float4 av = *reinterpret_cast<const float4*>(ap + 4 * u4);
                        e0 = fmaf(wreg[4*u4+0], av.x, e0);
                        e1 = fmaf(wreg[4*u4+1], av.y, e1);
                        e2 = fmaf(wreg[4*u4+2], av.z, e2);
                        e3 = fmaf(wreg[4*u4+3], av.w, e3);
                    }
                    e0 = fmaf(wreg[48], ap[48], e0);
                    e1 = fmaf(wreg[49], ap[49], e1);
                    rG = (e0 + e1) + (e2 + e3);                   // eAcc
                }
                if (t >= 400) {   // dx-early over ls
                    const float* aq = lsP + ((c3 == 3) ? 52 : 0);
                    float f0=0.f, f1=0.f, f2=0.f, f3=0.f;
                    #pragma unroll
                    for (int u4 = 0; u4 < 12; ++u4) {
                        const float4 av = *reinterpret_cast<const float4*>(aq + 4 * u4);
                        f0 = fmaf(wreg[50 + 4*u4 + 0], av.x, f0);
                        f1 = fmaf(wreg[50 + 4*u4 + 1], av.y, f1);
                        f2 = fmaf(wreg[50 + 4*u4 + 2], av.z, f2);
                        f3 = fmaf(wreg[50 + 4*u4 + 3], av.w, f3);
                    }
                    f0 = fmaf(wreg[98], aq[48], f0);
                    f1 = fmaf(wreg[99], aq[49], f1);
                    rH = (f0 + f1) + (f2 + f3);                   // dAcc
                }
            }
            if (t < 200) rpart[t] = wdS[t] * lsP[PF(t - (t < 100 ? 0 : 100))];
        } else if (t < 1000) {
            if (j < SEQ - 1) l1_row();
        } else if (t < 1019) {
            if (j + 3 < SEQ)
                xpN = *reinterpret_cast<const float4*>(x + ((size_t)blk * SEQ + (j + 3)) * IND + 4 * (t - 1000));
        }
        __syncthreads();
        // ===== B2: dx-late over s2(j) -> dxP; kin2P s2 copy; r2 reduce; xt(j+2) write =====
        if (t >= 400 && t < 800) {
            float val;
            if (c3 < 2) {
                const float* ap = s2P + ((c3 == 1) ? 52 : 0);
                float f0=0.f, f1=0.f, f2=0.f, f3=0.f;
                #pragma unroll
                for (int u4 = 0; u4 < 12; ++u4) {
                    const float4 av = *reinterpret_cast<const float4*>(ap + 4 * u4);
                    f0 = fmaf(wreg[50 + 4*u4 + 0], av.x, f0);
                    f1 = fmaf(wreg[50 + 4*u4 + 1], av.y, f1);
                    f2 = fmaf(wreg[50 + 4*u4 + 2], av.z, f2);
                    f3 = fmaf(wreg[50 + 4*u4 + 3], av.w, f3);
                }
                f0 = fmaf(wreg[98], ap[48], f0);
                f1 = fmaf(wreg[99], ap[49], f1);
                val = (f0 + f1) + (f2 + f3);
            } else {
                val = rH;
            }
            const float v1 = __shfl(val, lbase + 1, 64);
            const float v2 = __shfl(val, lbase + 2, 64);
            const float v3 = __shfl(val, lbase + 3, 64);
            if (c3 == 0) {
                const int rd = (t >> 2) - 100;
                const float dxv = ((val + v1) + (v2 + v3)) + bxS[rd];
                dxP[PF(rd)] = dxv;
            }
        } else if (t < 400) {
            if (c3 == 0) {                       // s2(j) -> kin2P window
                const int col = 50 + (t >> 2);
                const int w = (col >= 114) ? 3 : ((col >= 76) ? 2 : 1);
                kin2P[w][col - 38 * w] = rC;
            }
        } else if (t >= 1000) {
            if (t < 1008) {
                const int rr = t - 1000;
                float sV = 0.f;
                #pragma unroll
                for (int u = 0; u < 25; ++u) sV += rpart[25 * rr + u];
                r2[rr] = sV;
            }
            if (t < 1019 && j + 2 < SEQ)
                *reinterpret_cast<float4*>(&kin1P[4 * (t - 1000)]) = xpO;
        }
        __syncthreads();
        // ===== B3: stage2-late over dx; 8-lane gather -> sigmoids -> liquid; s1 copies; md =====
        if (t < 800) {
            float val;
            if (c3 < 2) {
                const float* ap = dxP + ((c3 == 1) ? 52 : 0);
                float e0=0.f, e1=0.f, e2=0.f, e3=0.f;
                #pragma unroll
                for (int u4 = 0; u4 < 12; ++u4) {
                    const float4 av = *reinterpret_cast<const float4*>(ap + 4 * u4);
                    e0 = fmaf(wreg[4*u4+0], av.x, e0);
                    e1 = fmaf(wreg[4*u4+1], av.y, e1);
                    e2 = fmaf(wreg[4*u4+2], av.z, e2);
                    e3 = fmaf(wreg[4*u4+3], av.w, e3);
                }
                e0 = fmaf(wreg[48], ap[48], e0);
                e1 = fmaf(wreg[49], ap[49], e1);
                val = (e0 + e1) + (e2 + e3);
            } else {
                val = rG;
            }
            const float s1_ = __shfl(val, lb8 + 1, 64);
            const float s2_ = __shfl(val, lb8 + 2, 64);
            const float s3_ = __shfl(val, lb8 + 3, 64);
            const float s4_ = __shfl(val, lb8 + 4, 64);
            const float s5_ = __shfl(val, lb8 + 5, 64);
            const float s6_ = __shfl(val, lb8 + 6, 64);
            const float s7_ = __shfl(val, lb8 + 7, 64);
            if ((t & 7) == 0) {
                const float preM = ((val + s1_) + (s2_ + s3_)) + bmS[r];
                const float preA = ((s4_ + s5_) + (s6_ + s7_)) + baS[r];
                const float tm = sigf(preM);
                const float ta = sigf(preA);
                const float dxv = dxP[PF(r)];
                const float lbN = ta * rJ + (1.f - ta) * rK;
                const float Bv  = 1.6f + 1.8f * lbN;
                const float lmN = rI * tm + (1.f - tm) * dxv - Bv * rK;
                const float lsN = (lmN - Bv > 0.f) ? 1.f : 0.f;
                rI = lmN; rJ = lbN; rK = lsN;
                lmP[PF(r)] = lmN; lbP[PF(r)] = lbN; lsP[PF(r)] = lsN;
            }
        } else if (t < 1000) {
            if ((t & 3) == 0 && j < SEQ - 1) {   // s1(j+1) -> kin buffers
                const int n1 = (t - 800) >> 2;
                kin1P[76 + n1] = rC;
                const int w = (n1 >= 38) ? 1 : 0;
                kin2P[w][n1 - 38 * w] = rC;
            }
        } else if ((t == 1020 || t == 1021) && j >= 1) {
            const int o = t - 1020;
            const float dot = ((r2[4*o] + r2[4*o+1]) + (r2[4*o+2] + r2[4*o+3])) + rG;
            rH = rF * rH + (1.f - rF) * dot;     // mdr
            if (j >= 2) rI += rH;                // accr
        }
        xpO = xpN;
        __syncthreads();
    }

    // ===== epilogue: readout of ls(SEQ-1) =====
    if (t < 200) rpart[t] = wdS[t] * lsP[PF(t - (t < 100 ? 0 : 100))];
    __syncthreads();
    if (t >= 1000 && t < 1008) {
        const int rr = t - 1000;
        float sV = 0.f;
        #pragma unroll
        for (int u = 0; u < 25; ++u) sV += rpart[25 * rr + u];
        r2[rr] = sV;
    }
    __syncthreads();
    if (t == 1020 || t == 1021) {
        const int o = t - 1020;
        const float dot = ((r2[4*o] + r2[4*o+1]) + (r2[4*o+2] + r2[4*o+3])) + rG;
        rH = rF * rH + (1.f - rF) * dot;
        rI += rH;
        out[blk * 2 + o] = rI;
    }
}

extern "C" void kernel_launch(void* const* d_in, const int* in_sizes, int n_in,
                              void* d_out, int out_size, void* d_ws, size_t ws_size,
                              hipStream_t stream) {
    const float* x      = (const float*)d_in[0];
    const float* W1     = (const float*)d_in[1];
    const float* b1     = (const float*)d_in[2];
    const float* tau_m1 = (const float*)d_in[3];
    const float* tau_n1 = (const float*)d_in[4];
    const float* W2     = (const float*)d_in[5];
    const float* b2     = (const float*)d_in[6];
    const float* tau_m2 = (const float*)d_in[7];
    const float* tau_n2 = (const float*)d_in[8];
    const float* Wx     = (const float*)d_in[9];
    const float* bx     = (const float*)d_in[10];
    const float* Wm     = (const float*)d_in[11];
    const float* bm     = (const float*)d_in[12];
    const float* Wa     = (const float*)d_in[13];
    const float* ba     = (const float*)d_in[14];
    const float* Wd     = (const float*)d_in[15];
    const float* bd     = (const float*)d_in[16];
    const float* tau_md = (const float*)d_in[17];
    float* out = (float*)d_out;

    const int batch = in_sizes[0] / (SEQ * IND);   // 256
    dhsnn_fwd<<<batch, 1024, 0, stream>>>(x, W1, b1, tau_m1, tau_n1,
                                          W2, b2, tau_m2, tau_n2,
                                          Wx, bx, Wm, bm, Wa, ba,
                                          Wd, bd, tau_md, out);
}

// Round 4
// 13811.674 us; speedup vs baseline: 2.6003x; 2.6003x over previous
//
#include <hip/hip_runtime.h>
#include <math.h>

#define SEQ 1000
#define IND 76

__device__ __forceinline__ float sigf(float v) { return 1.0f / (1.0f + expf(-v)); }

// 512 threads. Roles:
//  t<400:  q=t>>2 (neuron 0..99), c=t&3. L2 row t (38 masked w @wreg[0..37]);
//          stage2 row (c<2 ? Wm[q] : Wa[q]), half h=c&1: early cols (mem part) @[38..89],
//          late cols (dx part) @[90..141]; dx row q chunk c: early(ls) @[142..169],
//          late(s2) @[170..197]. Lane c==0 owns m2 (reg pB) and the liquid update (state in LDS).
//  t<200:  readout partial (1 FMA).
//  t in [400,419): x prefetch: issue phase A -> wreg[140..143], write phase B.
//  t in {420,421}: readout md owner (pA=mdr, pB=accr, wreg[130]=alpha_d, [131]=bd).
//  t in [424,432): r2 reduce (phase B).
//  t in [448,498): L1 neuron n=t-448 (4 rows in-thread, 128 w @[0..127], scalars @[128..138]),
//          pipelined one step ahead.
__global__ __launch_bounds__(512) void dhsnn_fwd(
    const float* __restrict__ x,
    const float* __restrict__ W1, const float* __restrict__ b1,
    const float* __restrict__ tau_m1, const float* __restrict__ tau_n1,
    const float* __restrict__ W2, const float* __restrict__ b2,
    const float* __restrict__ tau_m2, const float* __restrict__ tau_n2,
    const float* __restrict__ Wxp, const float* __restrict__ bxp,
    const float* __restrict__ Wm, const float* __restrict__ bm,
    const float* __restrict__ Wa, const float* __restrict__ ba,
    const float* __restrict__ Wd, const float* __restrict__ bd,
    const float* __restrict__ tau_md,
    float* __restrict__ out)
{
    const int t   = (int)threadIdx.x;
    const int blk = (int)blockIdx.x;

    __shared__ __align__(16) float kin1P[128];    // [0..75] xt(j+1), [76..125] s1(j), [126..127]=0
    __shared__ __align__(16) float kin2P[4][40];  // branch windows of [s1(50), s2(100)], [38..39]=0
    __shared__ __align__(16) float s2P[104];      // [100..103]=0
    __shared__ __align__(16) float dxP[104];
    __shared__ __align__(16) float lsP[104];
    __shared__ __align__(16) float lmP[104];
    __shared__ __align__(16) float lbP[104];
    __shared__ __align__(16) float rpart[200];
    __shared__ __align__(16) float r2[8];
    __shared__ float b2S[400], bt2S[400], al2S[100], bmS[100], baS[100], bxS[100], wdS[200];

    // ---- zero LDS ----
    for (int i = t; i < 128; i += 512) kin1P[i] = 0.f;
    for (int i = t; i < 160; i += 512) (&kin2P[0][0])[i] = 0.f;
    for (int i = t; i < 104; i += 512) { s2P[i]=0.f; dxP[i]=0.f; lsP[i]=0.f; lmP[i]=0.f; lbP[i]=0.f; }
    for (int i = t; i < 200; i += 512) rpart[i] = 0.f;
    if (t < 8) r2[t] = 0.f;
    // ---- scalar tables ----
    if (t < 400) { b2S[t] = b2[t]; bt2S[t] = sigf(tau_n2[t]); }
    if (t < 100) { al2S[t] = sigf(tau_m2[t]); bmS[t] = bm[t]; baS[t] = ba[t]; bxS[t] = bxp[t]; }
    if (t < 200) wdS[t] = Wd[(t < 100 ? 0 : 100) + (t % 100)];

    const int q     = t >> 2;
    const int c     = t & 3;
    const int lbase = (t & 63) & ~3;
    const int doff  = (c == 0) ? 0 : (4 + 24 * c);

    float wreg[198];
    float pA = 0.f, pB = 0.f, pC = 0.f, pD = 0.f;   // role-unioned persistent scalars

    // ---- weight init ----
    if (t < 400) {
        #pragma unroll
        for (int u = 0; u < 38; ++u) {
            const int gc = 38 * c + u;
            wreg[u] = (gc < 150) ? W2[t * 150 + gc] : 0.f;
        }
        const float* Wrow = ((c < 2) ? Wm : Wa) + q * 200;
        const int eoff = (c & 1) ? 52 : 0;
        #pragma unroll
        for (int u = 0; u < 52; ++u) {
            const int col = eoff + u;
            const bool ok = (col < 100);
            wreg[38 + u] = ok ? Wrow[100 + col] : 0.f;   // early: mem (lm/lb) cols
            wreg[90 + u] = ok ? Wrow[col] : 0.f;         // late: dx cols
        }
        const int dcnt = (c == 0) ? 28 : 24;
        #pragma unroll
        for (int u = 0; u < 28; ++u) {
            const int col = doff + u;
            const bool ok = (u < dcnt);
            wreg[142 + u] = ok ? Wxp[q * 200 + 100 + col] : 0.f;  // early: ls cols
            wreg[170 + u] = ok ? Wxp[q * 200 + col] : 0.f;        // late: s2 cols
        }
    } else if (t >= 448 && t < 498) {
        const int n = t - 448;
        #pragma unroll
        for (int k = 0; k < 4; ++k) {
            #pragma unroll
            for (int u = 0; u < 32; ++u) {
                const int gc = 32 * k + u;
                wreg[k * 32 + u] = (gc < 126) ? W1[(4 * n + k) * 126 + gc] : 0.f;
            }
            wreg[128 + k] = b1[4 * n + k];
            wreg[132 + k] = sigf(tau_n1[4 * n + k]);
        }
        wreg[136] = sigf(tau_m1[n]);
        wreg[137] = 0.f;   // m1
        wreg[138] = 0.f;   // s1
    } else if (t == 420 || t == 421) {
        wreg[130] = sigf(tau_md[t - 420]);   // alpha_d
        wreg[131] = bd[t - 420];             // bd
    }

    // L1 neuron step: kin1P = [xt, s1_prev]; d1 in pA..pD, m1/s1 in wreg[137..138]
    auto l1_step = [&]() {
        float pr0 = wreg[128], pr1 = wreg[129], pr2 = wreg[130], pr3 = wreg[131];
        #pragma unroll
        for (int u4 = 0; u4 < 8; ++u4) {
            const float4 a0 = *reinterpret_cast<const float4*>(&kin1P[ 0 + 4 * u4]);
            const float4 a1 = *reinterpret_cast<const float4*>(&kin1P[32 + 4 * u4]);
            const float4 a2 = *reinterpret_cast<const float4*>(&kin1P[64 + 4 * u4]);
            const float4 a3 = *reinterpret_cast<const float4*>(&kin1P[96 + 4 * u4]);
            pr0 = fmaf(wreg[      4*u4+0], a0.x, pr0); pr0 = fmaf(wreg[      4*u4+1], a0.y, pr0);
            pr0 = fmaf(wreg[      4*u4+2], a0.z, pr0); pr0 = fmaf(wreg[      4*u4+3], a0.w, pr0);
            pr1 = fmaf(wreg[ 32 + 4*u4+0], a1.x, pr1); pr1 = fmaf(wreg[ 32 + 4*u4+1], a1.y, pr1);
            pr1 = fmaf(wreg[ 32 + 4*u4+2], a1.z, pr1); pr1 = fmaf(wreg[ 32 + 4*u4+3], a1.w, pr1);
            pr2 = fmaf(wreg[ 64 + 4*u4+0], a2.x, pr2); pr2 = fmaf(wreg[ 64 + 4*u4+1], a2.y, pr2);
            pr2 = fmaf(wreg[ 64 + 4*u4+2], a2.z, pr2); pr2 = fmaf(wreg[ 64 + 4*u4+3], a2.w, pr2);
            pr3 = fmaf(wreg[ 96 + 4*u4+0], a3.x, pr3); pr3 = fmaf(wreg[ 96 + 4*u4+1], a3.y, pr3);
            pr3 = fmaf(wreg[ 96 + 4*u4+2], a3.z, pr3); pr3 = fmaf(wreg[ 96 + 4*u4+3], a3.w, pr3);
        }
        const float d0 = wreg[132] * pA + (1.f - wreg[132]) * pr0;
        const float d1 = wreg[133] * pB + (1.f - wreg[133]) * pr1;
        const float d2 = wreg[134] * pC + (1.f - wreg[134]) * pr2;
        const float d3 = wreg[135] * pD + (1.f - wreg[135]) * pr3;
        pA = d0; pB = d1; pC = d2; pD = d3;
        const float sum = ((d0 + d1) + d2) + d3;
        wreg[137] = wreg[136] * wreg[137] + (1.f - wreg[136]) * sum - wreg[138];
        wreg[138] = (wreg[137] - 1.0f > 0.f) ? 1.f : 0.f;
    };

    __syncthreads();
    if (t < 100) lbP[t] = 1.6f;
    if (t >= 400 && t < 419) {    // xt(0)
        *reinterpret_cast<float4*>(&kin1P[4 * (t - 400)]) =
            *reinterpret_cast<const float4*>(x + (size_t)blk * SEQ * IND + 4 * (t - 400));
    }
    __syncthreads();
    if (t >= 448 && t < 498) l1_step();   // step 0 (s1 part of kin1P is zeros)
    __syncthreads();
    if (t >= 448 && t < 498) {            // s1(0) -> kin buffers
        const int n = t - 448;
        kin1P[76 + n] = wreg[138];
        const int w = (n >= 38) ? 1 : 0;
        kin2P[w][n - 38 * w] = wreg[138];
    }
    if (t >= 400 && t < 419) {            // xt(1)
        *reinterpret_cast<float4*>(&kin1P[4 * (t - 400)]) =
            *reinterpret_cast<const float4*>(x + ((size_t)blk * SEQ + 1) * IND + 4 * (t - 400));
    }
    __syncthreads();

    for (int j = 0; j < SEQ; ++j) {
        // ===== Phase A: L2(j)+m2/s2; stage2-early(lm/lb); dx-early(ls); rpart; L1(j+1); x issue =====
        if (t < 400) {
            {   // L2 row t
                const float* kw = kin2P[c];
                float a0=0.f, a1=0.f, a2=0.f, a3=0.f;
                #pragma unroll
                for (int cc = 0; cc < 9; ++cc) {
                    const float4 av = *reinterpret_cast<const float4*>(kw + 4 * cc);
                    a0 = fmaf(wreg[4*cc + 0], av.x, a0);
                    a1 = fmaf(wreg[4*cc + 1], av.y, a1);
                    a2 = fmaf(wreg[4*cc + 2], av.z, a2);
                    a3 = fmaf(wreg[4*cc + 3], av.w, a3);
                }
                a0 = fmaf(wreg[36], kw[36], a0);
                a1 = fmaf(wreg[37], kw[37], a1);
                const float proj = b2S[t] + ((a0 + a1) + (a2 + a3));
                const float bt = bt2S[t];
                pA = bt * pA + (1.f - bt) * proj;            // d2
                const float d1 = __shfl(pA, lbase + 1, 64);
                const float d2 = __shfl(pA, lbase + 2, 64);
                const float d3 = __shfl(pA, lbase + 3, 64);
                if (c == 0) {
                    const float al = al2S[q];
                    const float sum = ((pA + d1) + d2) + d3;
                    const float s2prev = s2P[q];
                    pB = al * pB + (1.f - al) * sum - s2prev;       // m2
                    s2P[q] = (pB - 1.0f > 0.f) ? 1.f : 0.f;         // s2
                }
            }
            {   // stage2-early over lm (c<2) / lb (c>=2)
                const float* ap = ((c < 2) ? lmP : lbP) + ((c & 1) ? 52 : 0);
                float e0=0.f, e1=0.f, e2=0.f, e3=0.f;
                #pragma unroll
                for (int u4 = 0; u4 < 13; ++u4) {
                    const float4 av = *reinterpret_cast<const float4*>(ap + 4 * u4);
                    e0 = fmaf(wreg[38 + 4*u4 + 0], av.x, e0);
                    e1 = fmaf(wreg[38 + 4*u4 + 1], av.y, e1);
                    e2 = fmaf(wreg[38 + 4*u4 + 2], av.z, e2);
                    e3 = fmaf(wreg[38 + 4*u4 + 3], av.w, e3);
                }
                pC = (e0 + e1) + (e2 + e3);                  // eAcc
            }
            {   // dx-early over ls
                const float* aq = lsP + doff;
                float f0=0.f, f1=0.f, f2=0.f, f3=0.f;
                #pragma unroll
                for (int u4 = 0; u4 < 7; ++u4) {
                    const float4 av = *reinterpret_cast<const float4*>(aq + 4 * u4);
                    f0 = fmaf(wreg[142 + 4*u4 + 0], av.x, f0);
                    f1 = fmaf(wreg[142 + 4*u4 + 1], av.y, f1);
                    f2 = fmaf(wreg[142 + 4*u4 + 2], av.z, f2);
                    f3 = fmaf(wreg[142 + 4*u4 + 3], av.w, f3);
                }
                pD = (f0 + f1) + (f2 + f3);                  // dAcc
            }
            if (t < 200) rpart[t] = wdS[t] * lsP[t - (t < 100 ? 0 : 100)];
        } else if (t < 419) {
            if (j + 2 < SEQ) {
                const float4 v = *reinterpret_cast<const float4*>(
                    x + ((size_t)blk * SEQ + (j + 2)) * IND + 4 * (t - 400));
                wreg[140] = v.x; wreg[141] = v.y; wreg[142] = v.z; wreg[143] = v.w;
            }
        } else if (t >= 448 && t < 498) {
            if (j < SEQ - 1) l1_step();
        }
        __syncthreads();
        // ===== Phase B: dx-late over s2(j) -> dxP; kin2P s2 copy; r2 reduce; xt write =====
        if (t < 400) {
            const float* ap = s2P + doff;
            float f0=0.f, f1=0.f, f2=0.f, f3=0.f;
            #pragma unroll
            for (int u4 = 0; u4 < 7; ++u4) {
                const float4 av = *reinterpret_cast<const float4*>(ap + 4 * u4);
                f0 = fmaf(wreg[170 + 4*u4 + 0], av.x, f0);
                f1 = fmaf(wreg[170 + 4*u4 + 1], av.y, f1);
                f2 = fmaf(wreg[170 + 4*u4 + 2], av.z, f2);
                f3 = fmaf(wreg[170 + 4*u4 + 3], av.w, f3);
            }
            const float tot = ((f0 + f1) + (f2 + f3)) + pD;
            const float t1 = __shfl(tot, lbase + 1, 64);
            const float t2 = __shfl(tot, lbase + 2, 64);
            const float t3 = __shfl(tot, lbase + 3, 64);
            if (c == 0) {
                dxP[q] = ((tot + t1) + (t2 + t3)) + bxS[q];
                const int col = 50 + q;                      // s2 -> kin2P window
                const int w = (col >= 114) ? 3 : ((col >= 76) ? 2 : 1);
                kin2P[w][col - 38 * w] = s2P[q];
            }
        } else if (t < 419) {
            if (j + 2 < SEQ) {
                float4 v; v.x = wreg[140]; v.y = wreg[141]; v.z = wreg[142]; v.w = wreg[143];
                *reinterpret_cast<float4*>(&kin1P[4 * (t - 400)]) = v;
            }
        } else if (t >= 424 && t < 432) {
            const int rr = t - 424;
            float sV = 0.f;
            #pragma unroll
            for (int u = 0; u < 25; ++u) sV += rpart[25 * rr + u];
            r2[rr] = sV;
        }
        __syncthreads();
        // ===== Phase C: stage2-late over dx; gather -> sigmoids -> liquid; s1 copy; md =====
        if (t < 400) {
            const float* ap = dxP + ((c & 1) ? 52 : 0);
            float e0=0.f, e1=0.f, e2=0.f, e3=0.f;
            #pragma unroll
            for (int u4 = 0; u4 < 13; ++u4) {
                const float4 av = *reinterpret_cast<const float4*>(ap + 4 * u4);
                e0 = fmaf(wreg[90 + 4*u4 + 0], av.x, e0);
                e1 = fmaf(wreg[90 + 4*u4 + 1], av.y, e1);
                e2 = fmaf(wreg[90 + 4*u4 + 2], av.z, e2);
                e3 = fmaf(wreg[90 + 4*u4 + 3], av.w, e3);
            }
            const float tot = ((e0 + e1) + (e2 + e3)) + pC;
            const float t1 = __shfl(tot, lbase + 1, 64);
            const float t2 = __shfl(tot, lbase + 2, 64);
            const float t3 = __shfl(tot, lbase + 3, 64);
            if (c == 0) {
                const float tm = sigf((tot + t1) + bmS[q]);
                const float ta = sigf((t2 + t3) + baS[q]);
                const float lm = lmP[q], lb = lbP[q], ls = lsP[q], dxv = dxP[q];
                const float lbN = ta * lb + (1.f - ta) * ls;
                const float Bv  = 1.6f + 1.8f * lbN;
                const float lmN = lm * tm + (1.f - tm) * dxv - Bv * ls;
                const float lsN = (lmN - Bv > 0.f) ? 1.f : 0.f;
                lmP[q] = lmN; lbP[q] = lbN; lsP[q] = lsN;
            }
        } else if (t >= 448 && t < 498) {
            if (j < SEQ - 1) {                              // s1(j+1) -> kin buffers
                const int n = t - 448;
                kin1P[76 + n] = wreg[138];
                const int w = (n >= 38) ? 1 : 0;
                kin2P[w][n - 38 * w] = wreg[138];
            }
        } else if ((t == 420 || t == 421) && j >= 1) {
            const float dot = ((r2[4*(t-420)] + r2[4*(t-420)+1])
                             + (r2[4*(t-420)+2] + r2[4*(t-420)+3])) + wreg[131];
            pA = wreg[130] * pA + (1.f - wreg[130]) * dot;   // mdr
            if (j >= 2) pB += pA;                            // accr
        }
        __syncthreads();
    }

    // ===== epilogue: readout of ls(SEQ-1) =====
    if (t < 200) rpart[t] = wdS[t] * lsP[t - (t < 100 ? 0 : 100)];
    __syncthreads();
    if (t >= 424 && t < 432) {
        const int rr = t - 424;
        float sV = 0.f;
        #pragma unroll
        for (int u = 0; u < 25; ++u) sV += rpart[25 * rr + u];
        r2[rr] = sV;
    }
    __syncthreads();
    if (t == 420 || t == 421) {
        const int o = t - 420;
        const float dot = ((r2[4*o] + r2[4*o+1]) + (r2[4*o+2] + r2[4*o+3])) + wreg[131];
        pA = wreg[130] * pA + (1.f - wreg[130]) * dot;
        pB += pA;
        out[blk * 2 + o] = pB;
    }
}

extern "C" void kernel_launch(void* const* d_in, const int* in_sizes, int n_in,
                              void* d_out, int out_size, void* d_ws, size_t ws_size,
                              hipStream_t stream) {
    const float* x      = (const float*)d_in[0];
    const float* W1     = (const float*)d_in[1];
    const float* b1     = (const float*)d_in[2];
    const float* tau_m1 = (const float*)d_in[3];
    const float* tau_n1 = (const float*)d_in[4];
    const float* W2     = (const float*)d_in[5];
    const float* b2     = (const float*)d_in[6];
    const float* tau_m2 = (const float*)d_in[7];
    const float* tau_n2 = (const float*)d_in[8];
    const float* Wx     = (const float*)d_in[9];
    const float* bx     = (const float*)d_in[10];
    const float* Wm     = (const float*)d_in[11];
    const float* bm     = (const float*)d_in[12];
    const float* Wa     = (const float*)d_in[13];
    const float* ba     = (const float*)d_in[14];
    const float* Wd     = (const float*)d_in[15];
    const float* bd     = (const float*)d_in[16];
    const float* tau_md = (const float*)d_in[17];
    float* out = (float*)d_out;

    const int batch = in_sizes[0] / (SEQ * IND);   // 256
    dhsnn_fwd<<<batch, 512, 0, stream>>>(x, W1, b1, tau_m1, tau_n1,
                                         W2, b2, tau_m2, tau_n2,
                                         Wx, bx, Wm, bm, Wa, ba,
                                         Wd, bd, tau_md, out);
}

// Round 5
// 13007.080 us; speedup vs baseline: 2.7611x; 1.0619x over previous
//
#include <hip/hip_runtime.h>
#include <math.h>

#define SEQ 1000
#define IND 76

__device__ __forceinline__ float sigf(float v) { return 1.0f / (1.0f + expf(-v)); }

// One-time pack: w2pk[r][40] = masked branch window of W2 row r (38 cols, zero-padded to 40).
__global__ void pack_w2(const float* __restrict__ W2, float* __restrict__ w2pk) {
    const int i = blockIdx.x * 256 + threadIdx.x;
    if (i >= 400 * 40) return;
    const int r = i / 40, u = i - 40 * r;
    const int col = 38 * (r & 3) + u;
    w2pk[i] = (u < 38 && col < 150) ? W2[r * 150 + col] : 0.f;
}

// 512 threads. Roles:
//  t<400:  q=t>>2, c=t&3. L2 row t: weights streamed from w2pk (global, L2-resident).
//          stage2 row (c<2 ? Wm[q] : Wa[q]), half h=c&1: early (mem cols) @wreg[0..51],
//          late (dx cols) @wreg[52..103]; dx row q chunk c: early(ls) @[104..131],
//          late(s2) @[132..159]. Lane c==0 owns m2 (pB); liquid state in LDS.
//  t<200:  readout partial (1 FMA).
//  t in [400,419): x prefetch (float4 in xp), issue phase A, write phase B.
//  t in {420,421}: readout md owner (pA=mdr, pB=accr, wreg[130]=alpha_d, [131]=bd).
//  t in [424,432): r2 reduce (phase B).
//  t in [448,498): L1 neuron n=t-448 (128 w @[0..127], scalars @[128..138]), one step ahead.
__global__ __launch_bounds__(512, 2) void dhsnn_fwd(
    const float* __restrict__ x,
    const float* __restrict__ W1, const float* __restrict__ b1,
    const float* __restrict__ tau_m1, const float* __restrict__ tau_n1,
    const float* __restrict__ w2pk, const float* __restrict__ b2,
    const float* __restrict__ tau_m2, const float* __restrict__ tau_n2,
    const float* __restrict__ Wxp, const float* __restrict__ bxp,
    const float* __restrict__ Wm, const float* __restrict__ bm,
    const float* __restrict__ Wa, const float* __restrict__ ba,
    const float* __restrict__ Wd, const float* __restrict__ bd,
    const float* __restrict__ tau_md,
    float* __restrict__ out)
{
    const int t   = (int)threadIdx.x;
    const int blk = (int)blockIdx.x;

    __shared__ __align__(16) float kin1P[128];    // [0..75] xt(j+1), [76..125] s1(j), [126..127]=0
    __shared__ __align__(16) float kin2P[4][40];  // branch windows of [s1(50), s2(100)], [38..39]=0
    __shared__ __align__(16) float s2P[104];      // [100..103]=0
    __shared__ __align__(16) float dxP[104];
    __shared__ __align__(16) float lsP[104];
    __shared__ __align__(16) float lmP[104];
    __shared__ __align__(16) float lbP[104];
    __shared__ __align__(16) float rpart[200];
    __shared__ __align__(16) float r2[8];
    __shared__ float b2S[400], bt2S[400], al2S[100], bmS[100], baS[100], bxS[100], wdS[200];

    // ---- zero LDS ----
    for (int i = t; i < 128; i += 512) kin1P[i] = 0.f;
    for (int i = t; i < 160; i += 512) (&kin2P[0][0])[i] = 0.f;
    for (int i = t; i < 104; i += 512) { s2P[i]=0.f; dxP[i]=0.f; lsP[i]=0.f; lmP[i]=0.f; lbP[i]=0.f; }
    for (int i = t; i < 200; i += 512) rpart[i] = 0.f;
    if (t < 8) r2[t] = 0.f;
    // ---- scalar tables ----
    if (t < 400) { b2S[t] = b2[t]; bt2S[t] = sigf(tau_n2[t]); }
    if (t < 100) { al2S[t] = sigf(tau_m2[t]); bmS[t] = bm[t]; baS[t] = ba[t]; bxS[t] = bxp[t]; }
    if (t < 200) wdS[t] = Wd[(t < 100 ? 0 : 100) + (t % 100)];

    const int q     = t >> 2;
    const int c     = t & 3;
    const int lbase = (t & 63) & ~3;
    const int doff  = (c == 0) ? 0 : (4 + 24 * c);

    float wreg[160];
    float pA = 0.f, pB = 0.f, pC = 0.f, pD = 0.f;   // role-unioned persistent scalars
    float4 xp = make_float4(0.f, 0.f, 0.f, 0.f);

    // ---- weight init ----
    if (t < 400) {
        const float* Wrow = ((c < 2) ? Wm : Wa) + q * 200;
        const int eoff = (c & 1) ? 52 : 0;
        #pragma unroll
        for (int u = 0; u < 52; ++u) {
            const int col = eoff + u;
            const bool ok = (col < 100);
            wreg[u]      = ok ? Wrow[100 + col] : 0.f;   // stage2-early: mem (lm/lb) cols
            wreg[52 + u] = ok ? Wrow[col] : 0.f;         // stage2-late: dx cols
        }
        const int dcnt = (c == 0) ? 28 : 24;
        #pragma unroll
        for (int u = 0; u < 28; ++u) {
            const int col = doff + u;
            const bool ok = (u < dcnt);
            wreg[104 + u] = ok ? Wxp[q * 200 + 100 + col] : 0.f;  // dx-early: ls cols
            wreg[132 + u] = ok ? Wxp[q * 200 + col] : 0.f;        // dx-late: s2 cols
        }
    } else if (t >= 448 && t < 498) {
        const int n = t - 448;
        #pragma unroll
        for (int k = 0; k < 4; ++k) {
            #pragma unroll
            for (int u = 0; u < 32; ++u) {
                const int gc = 32 * k + u;
                wreg[k * 32 + u] = (gc < 126) ? W1[(4 * n + k) * 126 + gc] : 0.f;
            }
            wreg[128 + k] = b1[4 * n + k];
            wreg[132 + k] = sigf(tau_n1[4 * n + k]);
        }
        wreg[136] = sigf(tau_m1[n]);
        wreg[137] = 0.f;   // m1
        wreg[138] = 0.f;   // s1
    } else if (t == 420 || t == 421) {
        wreg[130] = sigf(tau_md[t - 420]);   // alpha_d
        wreg[131] = bd[t - 420];             // bd
    }

    // L1 neuron step: kin1P = [xt, s1_prev]
    auto l1_step = [&]() {
        float pr0 = wreg[128], pr1 = wreg[129], pr2 = wreg[130], pr3 = wreg[131];
        #pragma unroll
        for (int u4 = 0; u4 < 8; ++u4) {
            const float4 a0 = *reinterpret_cast<const float4*>(&kin1P[ 0 + 4 * u4]);
            const float4 a1 = *reinterpret_cast<const float4*>(&kin1P[32 + 4 * u4]);
            const float4 a2 = *reinterpret_cast<const float4*>(&kin1P[64 + 4 * u4]);
            const float4 a3 = *reinterpret_cast<const float4*>(&kin1P[96 + 4 * u4]);
            pr0 = fmaf(wreg[      4*u4+0], a0.x, pr0); pr0 = fmaf(wreg[      4*u4+1], a0.y, pr0);
            pr0 = fmaf(wreg[      4*u4+2], a0.z, pr0); pr0 = fmaf(wreg[      4*u4+3], a0.w, pr0);
            pr1 = fmaf(wreg[ 32 + 4*u4+0], a1.x, pr1); pr1 = fmaf(wreg[ 32 + 4*u4+1], a1.y, pr1);
            pr1 = fmaf(wreg[ 32 + 4*u4+2], a1.z, pr1); pr1 = fmaf(wreg[ 32 + 4*u4+3], a1.w, pr1);
            pr2 = fmaf(wreg[ 64 + 4*u4+0], a2.x, pr2); pr2 = fmaf(wreg[ 64 + 4*u4+1], a2.y, pr2);
            pr2 = fmaf(wreg[ 64 + 4*u4+2], a2.z, pr2); pr2 = fmaf(wreg[ 64 + 4*u4+3], a2.w, pr2);
            pr3 = fmaf(wreg[ 96 + 4*u4+0], a3.x, pr3); pr3 = fmaf(wreg[ 96 + 4*u4+1], a3.y, pr3);
            pr3 = fmaf(wreg[ 96 + 4*u4+2], a3.z, pr3); pr3 = fmaf(wreg[ 96 + 4*u4+3], a3.w, pr3);
        }
        const float d0 = wreg[132] * pA + (1.f - wreg[132]) * pr0;
        const float d1 = wreg[133] * pB + (1.f - wreg[133]) * pr1;
        const float d2 = wreg[134] * pC + (1.f - wreg[134]) * pr2;
        const float d3 = wreg[135] * pD + (1.f - wreg[135]) * pr3;
        pA = d0; pB = d1; pC = d2; pD = d3;
        const float sum = ((d0 + d1) + d2) + d3;
        wreg[137] = wreg[136] * wreg[137] + (1.f - wreg[136]) * sum - wreg[138];
        wreg[138] = (wreg[137] - 1.0f > 0.f) ? 1.f : 0.f;
    };

    __syncthreads();
    if (t < 100) lbP[t] = 1.6f;
    if (t >= 400 && t < 419) {    // xt(0)
        *reinterpret_cast<float4*>(&kin1P[4 * (t - 400)]) =
            *reinterpret_cast<const float4*>(x + (size_t)blk * SEQ * IND + 4 * (t - 400));
    }
    __syncthreads();
    if (t >= 448 && t < 498) l1_step();   // step 0 (s1 part of kin1P is zeros)
    __syncthreads();
    if (t >= 448 && t < 498) {            // s1(0) -> kin buffers
        const int n = t - 448;
        kin1P[76 + n] = wreg[138];
        const int w = (n >= 38) ? 1 : 0;
        kin2P[w][n - 38 * w] = wreg[138];
    }
    if (t >= 400 && t < 419) {            // xt(1)
        *reinterpret_cast<float4*>(&kin1P[4 * (t - 400)]) =
            *reinterpret_cast<const float4*>(x + ((size_t)blk * SEQ + 1) * IND + 4 * (t - 400));
    }
    __syncthreads();

    for (int j = 0; j < SEQ; ++j) {
        // ===== Phase A: L2(j)+m2/s2; stage2-early(lm/lb); dx-early(ls); rpart; L1(j+1); x issue =====
        if (t < 400) {
            {   // L2 row t, weights streamed from global (L2-cached)
                const float4* wrow = reinterpret_cast<const float4*>(w2pk + t * 40);
                const float* kw = kin2P[c];
                float a0=0.f, a1=0.f, a2=0.f, a3=0.f;
                #pragma unroll
                for (int cc = 0; cc < 10; ++cc) {
                    const float4 wv = wrow[cc];
                    const float4 av = *reinterpret_cast<const float4*>(kw + 4 * cc);
                    a0 = fmaf(wv.x, av.x, a0);
                    a1 = fmaf(wv.y, av.y, a1);
                    a2 = fmaf(wv.z, av.z, a2);
                    a3 = fmaf(wv.w, av.w, a3);
                }
                const float proj = b2S[t] + ((a0 + a1) + (a2 + a3));
                const float bt = bt2S[t];
                pA = bt * pA + (1.f - bt) * proj;            // d2
                const float d1 = __shfl(pA, lbase + 1, 64);
                const float d2 = __shfl(pA, lbase + 2, 64);
                const float d3 = __shfl(pA, lbase + 3, 64);
                if (c == 0) {
                    const float al = al2S[q];
                    const float sum = ((pA + d1) + d2) + d3;
                    const float s2prev = s2P[q];
                    pB = al * pB + (1.f - al) * sum - s2prev;       // m2
                    s2P[q] = (pB - 1.0f > 0.f) ? 1.f : 0.f;         // s2
                }
            }
            __builtin_amdgcn_sched_barrier(0);
            {   // stage2-early over lm (c<2) / lb (c>=2)
                const float* ap = ((c < 2) ? lmP : lbP) + ((c & 1) ? 52 : 0);
                float e0=0.f, e1=0.f, e2=0.f, e3=0.f;
                #pragma unroll
                for (int u4 = 0; u4 < 13; ++u4) {
                    const float4 av = *reinterpret_cast<const float4*>(ap + 4 * u4);
                    e0 = fmaf(wreg[4*u4 + 0], av.x, e0);
                    e1 = fmaf(wreg[4*u4 + 1], av.y, e1);
                    e2 = fmaf(wreg[4*u4 + 2], av.z, e2);
                    e3 = fmaf(wreg[4*u4 + 3], av.w, e3);
                }
                pC = (e0 + e1) + (e2 + e3);                  // eAcc
            }
            __builtin_amdgcn_sched_barrier(0);
            {   // dx-early over ls
                const float* aq = lsP + doff;
                float f0=0.f, f1=0.f, f2=0.f, f3=0.f;
                #pragma unroll
                for (int u4 = 0; u4 < 7; ++u4) {
                    const float4 av = *reinterpret_cast<const float4*>(aq + 4 * u4);
                    f0 = fmaf(wreg[104 + 4*u4 + 0], av.x, f0);
                    f1 = fmaf(wreg[104 + 4*u4 + 1], av.y, f1);
                    f2 = fmaf(wreg[104 + 4*u4 + 2], av.z, f2);
                    f3 = fmaf(wreg[104 + 4*u4 + 3], av.w, f3);
                }
                pD = (f0 + f1) + (f2 + f3);                  // dAcc
            }
            if (t < 200) rpart[t] = wdS[t] * lsP[t - (t < 100 ? 0 : 100)];
        } else if (t < 419) {
            if (j + 2 < SEQ)
                xp = *reinterpret_cast<const float4*>(
                    x + ((size_t)blk * SEQ + (j + 2)) * IND + 4 * (t - 400));
        } else if (t >= 448 && t < 498) {
            if (j < SEQ - 1) l1_step();
        }
        __syncthreads();
        // ===== Phase B: dx-late over s2(j) -> dxP; kin2P s2 copy; r2 reduce; xt write =====
        if (t < 400) {
            const float* ap = s2P + doff;
            float f0=0.f, f1=0.f, f2=0.f, f3=0.f;
            #pragma unroll
            for (int u4 = 0; u4 < 7; ++u4) {
                const float4 av = *reinterpret_cast<const float4*>(ap + 4 * u4);
                f0 = fmaf(wreg[132 + 4*u4 + 0], av.x, f0);
                f1 = fmaf(wreg[132 + 4*u4 + 1], av.y, f1);
                f2 = fmaf(wreg[132 + 4*u4 + 2], av.z, f2);
                f3 = fmaf(wreg[132 + 4*u4 + 3], av.w, f3);
            }
            const float tot = ((f0 + f1) + (f2 + f3)) + pD;
            const float t1 = __shfl(tot, lbase + 1, 64);
            const float t2 = __shfl(tot, lbase + 2, 64);
            const float t3 = __shfl(tot, lbase + 3, 64);
            if (c == 0) {
                dxP[q] = ((tot + t1) + (t2 + t3)) + bxS[q];
                const int col = 50 + q;                      // s2 -> kin2P window
                const int w = (col >= 114) ? 3 : ((col >= 76) ? 2 : 1);
                kin2P[w][col - 38 * w] = s2P[q];
            }
        } else if (t < 419) {
            if (j + 2 < SEQ)
                *reinterpret_cast<float4*>(&kin1P[4 * (t - 400)]) = xp;
        } else if (t >= 424 && t < 432) {
            const int rr = t - 424;
            float sV = 0.f;
            #pragma unroll
            for (int u = 0; u < 25; ++u) sV += rpart[25 * rr + u];
            r2[rr] = sV;
        }
        __syncthreads();
        // ===== Phase C: stage2-late over dx; gather -> sigmoids -> liquid; s1 copy; md =====
        if (t < 400) {
            const float* ap = dxP + ((c & 1) ? 52 : 0);
            float e0=0.f, e1=0.f, e2=0.f, e3=0.f;
            #pragma unroll
            for (int u4 = 0; u4 < 13; ++u4) {
                const float4 av = *reinterpret_cast<const float4*>(ap + 4 * u4);
                e0 = fmaf(wreg[52 + 4*u4 + 0], av.x, e0);
                e1 = fmaf(wreg[52 + 4*u4 + 1], av.y, e1);
                e2 = fmaf(wreg[52 + 4*u4 + 2], av.z, e2);
                e3 = fmaf(wreg[52 + 4*u4 + 3], av.w, e3);
            }
            const float tot = ((e0 + e1) + (e2 + e3)) + pC;
            const float t1 = __shfl(tot, lbase + 1, 64);
            const float t2 = __shfl(tot, lbase + 2, 64);
            const float t3 = __shfl(tot, lbase + 3, 64);
            if (c == 0) {
                const float tm = sigf((tot + t1) + bmS[q]);
                const float ta = sigf((t2 + t3) + baS[q]);
                const float lm = lmP[q], lb = lbP[q], ls = lsP[q], dxv = dxP[q];
                const float lbN = ta * lb + (1.f - ta) * ls;
                const float Bv  = 1.6f + 1.8f * lbN;
                const float lmN = lm * tm + (1.f - tm) * dxv - Bv * ls;
                const float lsN = (lmN - Bv > 0.f) ? 1.f : 0.f;
                lmP[q] = lmN; lbP[q] = lbN; lsP[q] = lsN;
            }
        } else if (t >= 448 && t < 498) {
            if (j < SEQ - 1) {                              // s1(j+1) -> kin buffers
                const int n = t - 448;
                kin1P[76 + n] = wreg[138];
                const int w = (n >= 38) ? 1 : 0;
                kin2P[w][n - 38 * w] = wreg[138];
            }
        } else if ((t == 420 || t == 421) && j >= 1) {
            const float dot = ((r2[4*(t-420)] + r2[4*(t-420)+1])
                             + (r2[4*(t-420)+2] + r2[4*(t-420)+3])) + wreg[131];
            pA = wreg[130] * pA + (1.f - wreg[130]) * dot;   // mdr
            if (j >= 2) pB += pA;                            // accr
        }
        __syncthreads();
    }

    // ===== epilogue: readout of ls(SEQ-1) =====
    if (t < 200) rpart[t] = wdS[t] * lsP[t - (t < 100 ? 0 : 100)];
    __syncthreads();
    if (t >= 424 && t < 432) {
        const int rr = t - 424;
        float sV = 0.f;
        #pragma unroll
        for (int u = 0; u < 25; ++u) sV += rpart[25 * rr + u];
        r2[rr] = sV;
    }
    __syncthreads();
    if (t == 420 || t == 421) {
        const int o = t - 420;
        const float dot = ((r2[4*o] + r2[4*o+1]) + (r2[4*o+2] + r2[4*o+3])) + wreg[131];
        pA = wreg[130] * pA + (1.f - wreg[130]) * dot;
        pB += pA;
        out[blk * 2 + o] = pB;
    }
}

extern "C" void kernel_launch(void* const* d_in, const int* in_sizes, int n_in,
                              void* d_out, int out_size, void* d_ws, size_t ws_size,
                              hipStream_t stream) {
    const float* x      = (const float*)d_in[0];
    const float* W1     = (const float*)d_in[1];
    const float* b1     = (const float*)d_in[2];
    const float* tau_m1 = (const float*)d_in[3];
    const float* tau_n1 = (const float*)d_in[4];
    const float* W2     = (const float*)d_in[5];
    const float* b2     = (const float*)d_in[6];
    const float* tau_m2 = (const float*)d_in[7];
    const float* tau_n2 = (const float*)d_in[8];
    const float* Wx     = (const float*)d_in[9];
    const float* bx     = (const float*)d_in[10];
    const float* Wm     = (const float*)d_in[11];
    const float* bm     = (const float*)d_in[12];
    const float* Wa     = (const float*)d_in[13];
    const float* ba     = (const float*)d_in[14];
    const float* Wd     = (const float*)d_in[15];
    const float* bd     = (const float*)d_in[16];
    const float* tau_md = (const float*)d_in[17];
    float* out = (float*)d_out;
    float* w2pk = (float*)d_ws;   // 400*40*4 = 64 KB

    pack_w2<<<(400 * 40 + 255) / 256, 256, 0, stream>>>(W2, w2pk);

    const int batch = in_sizes[0] / (SEQ * IND);   // 256
    dhsnn_fwd<<<batch, 512, 0, stream>>>(x, W1, b1, tau_m1, tau_n1,
                                         w2pk, b2, tau_m2, tau_n2,
                                         Wx, bx, Wm, bm, Wa, ba,
                                         Wd, bd, tau_md, out);
}

// Round 6
// 4712.605 us; speedup vs baseline: 7.6209x; 2.7601x over previous
//
#include <hip/hip_runtime.h>
#include <math.h>

#define SEQ 1000
#define IND 76
#define PIDX(i) ((((i)/25)*28) + ((i)%25))   // 25-chunk -> 28-stride padded layout

__device__ __forceinline__ float sigf(float v) { return 1.0f / (1.0f + expf(-v)); }

// w2pk[r][40]: masked branch window of W2 row r (38 cols, zero-padded to 40).
__global__ void pack_w2(const float* __restrict__ W2, float* __restrict__ w2pk) {
    const int i = blockIdx.x * 256 + threadIdx.x;
    if (i >= 400 * 40) return;
    const int r = i / 40, u = i - 40 * r;
    const int col = 38 * (r & 3) + u;
    w2pk[i] = (u < 38 && col < 150) ? W2[r * 150 + col] : 0.f;
}

// wxpk[part][slot][64]: part0 = early (ls cols 100..199), part1 = late (s2 cols 0..99).
// slot s: g=s>>2, c=s&3; rows 2g,2g+1; cols 25c..25c+24. row0 @[0..24], row1 @[28..52].
__global__ void pack_wx(const float* __restrict__ Wx, float* __restrict__ wxpk) {
    const int i = blockIdx.x * 256 + threadIdx.x;
    if (i >= 2 * 200 * 64) return;
    const int p = i / (200 * 64);
    const int rem = i - p * 200 * 64;
    const int s = rem / 64, u = rem - 64 * s;
    const int g = s >> 2, c = s & 3;
    const int j = (u >= 28) ? 1 : 0;
    const int local = u - 28 * j;
    float v = 0.f;
    if (local < 25) {
        const int col = (p == 0 ? 100 : 0) + 25 * c + local;
        v = Wx[(2 * g + j) * 200 + col];
    }
    wxpk[i] = v;
}

// 512 threads. Roles:
//  t<400:       L2 row t (w2pk streamed); pA=d2; c==0 owns m2 (pB).
//  t<200 (early): stage2-early regs wreg[0..99] (rows 2g,2g+1 of Wm + of Wa, 25-col chunk c,
//               mem cols 100+); dx-early streamed (wxpk part0); writes sEarly/dxEarly/rpart.
//  t in[200,400) (late): stage2-late regs wreg[0..99] (dx cols); dx-late streamed (part1);
//               lanes c<2 own liquid row 2g+c (state in LDS).
//  t in[400,500): L1 thread m=t-400: rows 2m,2m+1 (branch-masked, 32 cols each) in
//               wreg[0..63]; pC,pD = d-states; even thread owns m1/s1 (mA,mS).
//  t in[500,512): x prefetch (2 quads); [500,508): r2 reduce; {508,509}: readout md.
__global__ __launch_bounds__(512) void dhsnn_fwd(
    const float* __restrict__ x,
    const float* __restrict__ W1, const float* __restrict__ b1,
    const float* __restrict__ tau_m1, const float* __restrict__ tau_n1,
    const float* __restrict__ b2, const float* __restrict__ tau_m2,
    const float* __restrict__ tau_n2,
    const float* __restrict__ bxp, const float* __restrict__ bm,
    const float* __restrict__ ba,
    const float* __restrict__ Wm, const float* __restrict__ Wa,
    const float* __restrict__ Wd, const float* __restrict__ bd,
    const float* __restrict__ tau_md,
    const float* __restrict__ w2pk, const float* __restrict__ wxpk,
    float* __restrict__ out)
{
    const int t   = (int)threadIdx.x;
    const int blk = (int)blockIdx.x;

    __shared__ __align__(16) float kin1P[128];    // [0..75] xt(j+1), [76..125] s1(j), [126..127]=0
    __shared__ __align__(16) float kin2P[4][40];  // windows of [s1(50), s2(100)]
    __shared__ __align__(16) float s2P[112];      // PIDX layout
    __shared__ __align__(16) float dxP[112];
    __shared__ __align__(16) float lsP[112];
    __shared__ __align__(16) float lmP[112];
    __shared__ __align__(16) float lbP[112];
    __shared__ __align__(16) float sEarly[200];
    __shared__ __align__(16) float dxEarly[100];
    __shared__ __align__(16) float rpart[200];
    __shared__ __align__(16) float r2[8];
    __shared__ float b2S[400], bt2S[400], al2S[100], bmS[100], baS[100], bxS[100];
    __shared__ float wdS[200], b1S[200], bt1S[200], al1S[50];

    // ---- zero LDS ----
    for (int i = t; i < 128; i += 512) kin1P[i] = 0.f;
    for (int i = t; i < 160; i += 512) (&kin2P[0][0])[i] = 0.f;
    for (int i = t; i < 112; i += 512) { s2P[i]=0.f; dxP[i]=0.f; lsP[i]=0.f; lmP[i]=0.f; lbP[i]=0.f; }
    for (int i = t; i < 200; i += 512) { sEarly[i] = 0.f; rpart[i] = 0.f; }
    for (int i = t; i < 100; i += 512) dxEarly[i] = 0.f;
    if (t < 8) r2[t] = 0.f;
    // ---- scalar tables ----
    if (t < 400) { b2S[t] = b2[t]; bt2S[t] = sigf(tau_n2[t]); }
    if (t < 100) { al2S[t] = sigf(tau_m2[t]); bmS[t] = bm[t]; baS[t] = ba[t]; bxS[t] = bxp[t]; }
    if (t < 200) { wdS[t] = Wd[(t < 100 ? 0 : 100) + (t % 100)];
                   b1S[t] = b1[t]; bt1S[t] = sigf(tau_n1[t]); }
    if (t < 50)  al1S[t] = sigf(tau_m1[t]);

    const int c     = t & 3;
    const int lbase = (t & 63) & ~3;

    float wreg[100];
    float pA = 0.f, pB = 0.f, pC = 0.f, pD = 0.f;  // d2/m2 (t<400); d-row0/d-row1 (L1)
    float mA = 0.f, mS = 0.f;                      // L1 m1/s1 (even L1 threads); md: mdr/accr
    float4 xq0 = make_float4(0,0,0,0), xq1 = make_float4(0,0,0,0);

    // ---- weight init ----
    if (t < 400) {
        const bool late = (t >= 200);
        const int  sg   = late ? ((t - 200) >> 2) : (t >> 2);
        const int  colb = (late ? 0 : 100) + 25 * c;
        const int  r0 = 2 * sg, r1 = 2 * sg + 1;
        #pragma unroll
        for (int u = 0; u < 25; ++u) {
            wreg[u]      = Wm[r0 * 200 + colb + u];
            wreg[25 + u] = Wm[r1 * 200 + colb + u];
            wreg[50 + u] = Wa[r0 * 200 + colb + u];
            wreg[75 + u] = Wa[r1 * 200 + colb + u];
        }
    } else if (t < 500) {
        const int m = t - 400;
        const int rA_ = 2 * m, rB_ = 2 * m + 1;
        const int kA = rA_ & 3, kB = rB_ & 3;
        #pragma unroll
        for (int u = 0; u < 32; ++u) {
            const int cA = 32 * kA + u, cB = 32 * kB + u;
            wreg[u]      = (cA < 126) ? W1[rA_ * 126 + cA] : 0.f;
            wreg[32 + u] = (cB < 126) ? W1[rB_ * 126 + cB] : 0.f;
        }
    } else if (t == 508 || t == 509) {
        pC = sigf(tau_md[t - 508]);   // alpha_d
        pD = bd[t - 508];             // bd
    }

    // L1 step (bit-exact R1 ordering): kin1P = [xt, s1_prev]
    auto l1_step = [&]() {
        const int m = t - 400;
        const float* a0p = kin1P + 32 * ((2 * m) & 3);
        const float* a1p = kin1P + 32 * ((2 * m + 1) & 3);
        float acc0 = b1S[2 * m], acc1 = b1S[2 * m + 1];
        #pragma unroll
        for (int u4 = 0; u4 < 8; ++u4) {
            const float4 av = *reinterpret_cast<const float4*>(a0p + 4 * u4);
            acc0 = fmaf(wreg[4*u4+0], av.x, acc0); acc0 = fmaf(wreg[4*u4+1], av.y, acc0);
            acc0 = fmaf(wreg[4*u4+2], av.z, acc0); acc0 = fmaf(wreg[4*u4+3], av.w, acc0);
        }
        #pragma unroll
        for (int u4 = 0; u4 < 8; ++u4) {
            const float4 av = *reinterpret_cast<const float4*>(a1p + 4 * u4);
            acc1 = fmaf(wreg[32+4*u4+0], av.x, acc1); acc1 = fmaf(wreg[32+4*u4+1], av.y, acc1);
            acc1 = fmaf(wreg[32+4*u4+2], av.z, acc1); acc1 = fmaf(wreg[32+4*u4+3], av.w, acc1);
        }
        const float b0 = bt1S[2 * m], b1v = bt1S[2 * m + 1];
        pC = b0 * pC + (1.f - b0) * acc0;
        pD = b1v * pD + (1.f - b1v) * acc1;
        const float pCo = __shfl(pC, (t & 63) | 1, 64);
        const float pDo = __shfl(pD, (t & 63) | 1, 64);
        if ((t & 1) == 0) {
            const float sum = ((pC + pD) + pCo) + pDo;
            const float al = al1S[m >> 1];
            mA = al * mA + (1.f - al) * sum - mS;
            mS = (mA - 1.0f > 0.f) ? 1.f : 0.f;
        }
    };

    __syncthreads();
    if (t < 100) lbP[PIDX(t)] = 1.6f;               // bth init = b_j0
    if (t >= 500) {                                 // xt(0)
        const int i0 = t - 500;
        const float* xb = x + (size_t)blk * SEQ * IND;
        *reinterpret_cast<float4*>(&kin1P[4 * i0]) =
            *reinterpret_cast<const float4*>(xb + 4 * i0);
        if (i0 < 7)
            *reinterpret_cast<float4*>(&kin1P[4 * (i0 + 12)]) =
                *reinterpret_cast<const float4*>(xb + 4 * (i0 + 12));
    }
    __syncthreads();
    if (t >= 400 && t < 500) l1_step();             // s1(0) from [xt(0), 0]
    __syncthreads();
    if (t >= 400 && t < 500 && (t & 1) == 0) {      // s1(0) -> kin buffers
        const int n = (t - 400) >> 1;
        kin1P[76 + n] = mS;
        const int w = (n >= 38) ? 1 : 0;
        kin2P[w][n - 38 * w] = mS;
    }
    if (t >= 500) {                                 // xt(1)
        const int i0 = t - 500;
        const float* xb = x + ((size_t)blk * SEQ + 1) * IND;
        *reinterpret_cast<float4*>(&kin1P[4 * i0]) =
            *reinterpret_cast<const float4*>(xb + 4 * i0);
        if (i0 < 7)
            *reinterpret_cast<float4*>(&kin1P[4 * (i0 + 12)]) =
                *reinterpret_cast<const float4*>(xb + 4 * (i0 + 12));
    }
    __syncthreads();

    for (int j = 0; j < SEQ; ++j) {
        // ===== Phase A =====
        if (t < 400) {
            // L2 row t (streamed w2pk) -> d2 -> shfl -> m2/s2 at c==0
            const float4* wrow = reinterpret_cast<const float4*>(w2pk + t * 40);
            const float* kw = kin2P[c];
            float a0=0.f, a1=0.f, a2=0.f, a3=0.f;
            #pragma unroll
            for (int cc = 0; cc < 10; ++cc) {
                const float4 wv = wrow[cc];
                const float4 av = *reinterpret_cast<const float4*>(kw + 4 * cc);
                a0 = fmaf(wv.x, av.x, a0); a1 = fmaf(wv.y, av.y, a1);
                a2 = fmaf(wv.z, av.z, a2); a3 = fmaf(wv.w, av.w, a3);
            }
            const float proj = b2S[t] + ((a0 + a1) + (a2 + a3));
            const float bt = bt2S[t];
            pA = bt * pA + (1.f - bt) * proj;
            const float d1 = __shfl(pA, lbase + 1, 64);
            const float d2 = __shfl(pA, lbase + 2, 64);
            const float d3 = __shfl(pA, lbase + 3, 64);
            if (c == 0) {
                const int q = t >> 2;
                const float al = al2S[q];
                const float sum = ((pA + d1) + d2) + d3;
                pB = al * pB + (1.f - al) * sum - s2P[PIDX(q)];
                s2P[PIDX(q)] = (pB - 1.0f > 0.f) ? 1.f : 0.f;
            }
        }
        if (t < 200) {
            const int g = t >> 2;
            {   // stage2-early: rows (Wm 2g, Wm 2g+1, Wa 2g, Wa 2g+1), chunk c, acts lm/lb
                const float* apM = lmP + 28 * c;
                const float* apA = lbP + 28 * c;
                float P0=0.f, P1=0.f, P2=0.f, P3=0.f;
                #pragma unroll
                for (int u4 = 0; u4 < 6; ++u4) {
                    const float4 am = *reinterpret_cast<const float4*>(apM + 4 * u4);
                    const float4 aa = *reinterpret_cast<const float4*>(apA + 4 * u4);
                    P0 = fmaf(wreg[   4*u4+0], am.x, P0); P0 = fmaf(wreg[   4*u4+1], am.y, P0);
                    P0 = fmaf(wreg[   4*u4+2], am.z, P0); P0 = fmaf(wreg[   4*u4+3], am.w, P0);
                    P1 = fmaf(wreg[25+4*u4+0], am.x, P1); P1 = fmaf(wreg[25+4*u4+1], am.y, P1);
                    P1 = fmaf(wreg[25+4*u4+2], am.z, P1); P1 = fmaf(wreg[25+4*u4+3], am.w, P1);
                    P2 = fmaf(wreg[50+4*u4+0], aa.x, P2); P2 = fmaf(wreg[50+4*u4+1], aa.y, P2);
                    P2 = fmaf(wreg[50+4*u4+2], aa.z, P2); P2 = fmaf(wreg[50+4*u4+3], aa.w, P2);
                    P3 = fmaf(wreg[75+4*u4+0], aa.x, P3); P3 = fmaf(wreg[75+4*u4+1], aa.y, P3);
                    P3 = fmaf(wreg[75+4*u4+2], aa.z, P3); P3 = fmaf(wreg[75+4*u4+3], aa.w, P3);
                }
                P0 = fmaf(wreg[24], apM[24], P0); P1 = fmaf(wreg[49], apM[24], P1);
                P2 = fmaf(wreg[74], apA[24], P2); P3 = fmaf(wreg[99], apA[24], P3);
                float Q0 = P0 + __shfl_xor(P0, 1, 64), Q1 = P1 + __shfl_xor(P1, 1, 64);
                float Q2 = P2 + __shfl_xor(P2, 1, 64), Q3 = P3 + __shfl_xor(P3, 1, 64);
                float R0 = Q0 + __shfl_xor(Q0, 2, 64), R1 = Q1 + __shfl_xor(Q1, 2, 64);
                float R2 = Q2 + __shfl_xor(Q2, 2, 64), R3 = Q3 + __shfl_xor(Q3, 2, 64);
                sEarly[t] = (c == 0) ? R0 : (c == 1) ? R1 : (c == 2) ? R2 : R3;
            }
            {   // dx-early over ls (streamed wxpk part0)
                const float* wE = wxpk + (size_t)t * 64;
                const float* aq = lsP + 28 * c;
                float f0 = 0.f, f1 = 0.f;
                #pragma unroll
                for (int u4 = 0; u4 < 6; ++u4) {
                    const float4 w0v = *reinterpret_cast<const float4*>(wE + 4 * u4);
                    const float4 w1v = *reinterpret_cast<const float4*>(wE + 28 + 4 * u4);
                    const float4 av  = *reinterpret_cast<const float4*>(aq + 4 * u4);
                    f0 = fmaf(w0v.x, av.x, f0); f0 = fmaf(w0v.y, av.y, f0);
                    f0 = fmaf(w0v.z, av.z, f0); f0 = fmaf(w0v.w, av.w, f0);
                    f1 = fmaf(w1v.x, av.x, f1); f1 = fmaf(w1v.y, av.y, f1);
                    f1 = fmaf(w1v.z, av.z, f1); f1 = fmaf(w1v.w, av.w, f1);
                }
                f0 = fmaf(wE[24], aq[24], f0);
                f1 = fmaf(wE[52], aq[24], f1);
                float Qf0 = f0 + __shfl_xor(f0, 1, 64), Qf1 = f1 + __shfl_xor(f1, 1, 64);
                float Rf0 = Qf0 + __shfl_xor(Qf0, 2, 64), Rf1 = Qf1 + __shfl_xor(Qf1, 2, 64);
                if (c == 0) dxEarly[2 * g] = Rf0;
                else if (c == 1) dxEarly[2 * g + 1] = Rf1;
            }
            rpart[t] = wdS[t] * lsP[PIDX(t - (t < 100 ? 0 : 100))];
        } else if (t >= 400 && t < 500) {
            if (j < SEQ - 1) l1_step();
        } else if (t >= 500) {
            if (j + 2 < SEQ) {
                const int i0 = t - 500;
                const float* xb = x + ((size_t)blk * SEQ + (j + 2)) * IND;
                xq0 = *reinterpret_cast<const float4*>(xb + 4 * i0);
                if (i0 < 7) xq1 = *reinterpret_cast<const float4*>(xb + 4 * (i0 + 12));
            }
        }
        __syncthreads();
        // ===== Phase B: dx-late over s2(j); kin2P s2 copy; r2; xt write =====
        if (t >= 200 && t < 400) {
            const int s = t - 200, g = s >> 2;
            const float* wL = wxpk + (size_t)(200 + s) * 64;
            const float* aq = s2P + 28 * c;
            float f0 = 0.f, f1 = 0.f;
            #pragma unroll
            for (int u4 = 0; u4 < 6; ++u4) {
                const float4 w0v = *reinterpret_cast<const float4*>(wL + 4 * u4);
                const float4 w1v = *reinterpret_cast<const float4*>(wL + 28 + 4 * u4);
                const float4 av  = *reinterpret_cast<const float4*>(aq + 4 * u4);
                f0 = fmaf(w0v.x, av.x, f0); f0 = fmaf(w0v.y, av.y, f0);
                f0 = fmaf(w0v.z, av.z, f0); f0 = fmaf(w0v.w, av.w, f0);
                f1 = fmaf(w1v.x, av.x, f1); f1 = fmaf(w1v.y, av.y, f1);
                f1 = fmaf(w1v.z, av.z, f1); f1 = fmaf(w1v.w, av.w, f1);
            }
            f0 = fmaf(wL[24], aq[24], f0);
            f1 = fmaf(wL[52], aq[24], f1);
            float Qf0 = f0 + __shfl_xor(f0, 1, 64), Qf1 = f1 + __shfl_xor(f1, 1, 64);
            float Rf0 = Qf0 + __shfl_xor(Qf0, 2, 64), Rf1 = Qf1 + __shfl_xor(Qf1, 2, 64);
            if (c == 0)      dxP[PIDX(2 * g)]     = (Rf0 + dxEarly[2 * g])     + bxS[2 * g];
            else if (c == 1) dxP[PIDX(2 * g + 1)] = (Rf1 + dxEarly[2 * g + 1]) + bxS[2 * g + 1];
        } else if (t < 200) {
            if (c == 0) {                          // s2(j) -> kin2P window
                const int q = t >> 2;              // covers q 0..49; late owners cover 50..99
                const int col = 50 + q;
                const int w = (col >= 114) ? 3 : ((col >= 76) ? 2 : 1);
                kin2P[w][col - 38 * w] = s2P[PIDX(q)];
            }
        } else if (t >= 500) {
            if (t < 508) {
                const int rr = t - 500;
                float sV = 0.f;
                #pragma unroll
                for (int u = 0; u < 25; ++u) sV += rpart[25 * rr + u];
                r2[rr] = sV;
            }
            if (j + 2 < SEQ) {
                const int i0 = t - 500;
                *reinterpret_cast<float4*>(&kin1P[4 * i0]) = xq0;
                if (i0 < 7) *reinterpret_cast<float4*>(&kin1P[4 * (i0 + 12)]) = xq1;
            }
        }
        // late-owner kin2P copy (q 50..99) — must run for t in [200,400), c==0
        if (t >= 200 && t < 400 && c == 0) {
            const int q = t >> 2;
            const int col = 50 + q;
            const int w = (col >= 114) ? 3 : ((col >= 76) ? 2 : 1);
            kin2P[w][col - 38 * w] = s2P[PIDX(q)];
        }
        __syncthreads();
        // ===== Phase C: stage2-late over dx -> sigmoids -> liquid; s1 copy; md =====
        if (t >= 200 && t < 400) {
            const int s = t - 200, g = s >> 2;
            const float* apD = dxP + 28 * c;
            float P0=0.f, P1=0.f, P2=0.f, P3=0.f;
            #pragma unroll
            for (int u4 = 0; u4 < 6; ++u4) {
                const float4 ad = *reinterpret_cast<const float4*>(apD + 4 * u4);
                P0 = fmaf(wreg[   4*u4+0], ad.x, P0); P0 = fmaf(wreg[   4*u4+1], ad.y, P0);
                P0 = fmaf(wreg[   4*u4+2], ad.z, P0); P0 = fmaf(wreg[   4*u4+3], ad.w, P0);
                P1 = fmaf(wreg[25+4*u4+0], ad.x, P1); P1 = fmaf(wreg[25+4*u4+1], ad.y, P1);
                P1 = fmaf(wreg[25+4*u4+2], ad.z, P1); P1 = fmaf(wreg[25+4*u4+3], ad.w, P1);
                P2 = fmaf(wreg[50+4*u4+0], ad.x, P2); P2 = fmaf(wreg[50+4*u4+1], ad.y, P2);
                P2 = fmaf(wreg[50+4*u4+2], ad.z, P2); P2 = fmaf(wreg[50+4*u4+3], ad.w, P2);
                P3 = fmaf(wreg[75+4*u4+0], ad.x, P3); P3 = fmaf(wreg[75+4*u4+1], ad.y, P3);
                P3 = fmaf(wreg[75+4*u4+2], ad.z, P3); P3 = fmaf(wreg[75+4*u4+3], ad.w, P3);
            }
            P0 = fmaf(wreg[24], apD[24], P0); P1 = fmaf(wreg[49], apD[24], P1);
            P2 = fmaf(wreg[74], apD[24], P2); P3 = fmaf(wreg[99], apD[24], P3);
            float Q0 = P0 + __shfl_xor(P0, 1, 64), Q1 = P1 + __shfl_xor(P1, 1, 64);
            float Q2 = P2 + __shfl_xor(P2, 1, 64), Q3 = P3 + __shfl_xor(P3, 1, 64);
            float R0 = Q0 + __shfl_xor(Q0, 2, 64), R1 = Q1 + __shfl_xor(Q1, 2, 64);
            float R2 = Q2 + __shfl_xor(Q2, 2, 64), R3 = Q3 + __shfl_xor(Q3, 2, 64);
            const float sel  = (c == 0) ? R0 : (c == 1) ? R1 : (c == 2) ? R2 : R3;
            const float bias = (c < 2) ? bmS[2 * g + c] : baS[2 * g + c - 2];
            const float tv = sigf((sel + sEarly[s]) + bias);
            const float taP = __shfl(tv, lbase + 2 + (c & 1), 64);
            if (c < 2) {
                const int rq = 2 * g + c;
                const float lm = lmP[PIDX(rq)], lb = lbP[PIDX(rq)];
                const float ls = lsP[PIDX(rq)], dxv = dxP[PIDX(rq)];
                const float lbN = taP * lb + (1.f - taP) * ls;
                const float Bv  = 1.6f + 1.8f * lbN;
                const float lmN = lm * tv + (1.f - tv) * dxv - Bv * ls;
                const float lsN = (lmN - Bv > 0.f) ? 1.f : 0.f;
                lmP[PIDX(rq)] = lmN; lbP[PIDX(rq)] = lbN; lsP[PIDX(rq)] = lsN;
            }
        } else if (t >= 400 && t < 500) {
            if ((t & 1) == 0 && j < SEQ - 1) {      // s1(j+1) -> kin buffers
                const int n = (t - 400) >> 1;
                kin1P[76 + n] = mS;
                const int w = (n >= 38) ? 1 : 0;
                kin2P[w][n - 38 * w] = mS;
            }
        } else if ((t == 508 || t == 509) && j >= 1) {
            const int o = t - 508;
            const float dot = ((r2[4*o] + r2[4*o+1]) + (r2[4*o+2] + r2[4*o+3])) + pD;
            mA = pC * mA + (1.f - pC) * dot;        // mdr
            if (j >= 2) mS += mA;                   // accr
        }
        __syncthreads();
    }

    // ===== epilogue: readout of ls(SEQ-1) =====
    if (t < 200) rpart[t] = wdS[t] * lsP[PIDX(t - (t < 100 ? 0 : 100))];
    __syncthreads();
    if (t >= 500 && t < 508) {
        const int rr = t - 500;
        float sV = 0.f;
        #pragma unroll
        for (int u = 0; u < 25; ++u) sV += rpart[25 * rr + u];
        r2[rr] = sV;
    }
    __syncthreads();
    if (t == 508 || t == 509) {
        const int o = t - 508;
        const float dot = ((r2[4*o] + r2[4*o+1]) + (r2[4*o+2] + r2[4*o+3])) + pD;
        mA = pC * mA + (1.f - pC) * dot;
        mS += mA;
        out[blk * 2 + o] = mS;
    }
}

extern "C" void kernel_launch(void* const* d_in, const int* in_sizes, int n_in,
                              void* d_out, int out_size, void* d_ws, size_t ws_size,
                              hipStream_t stream) {
    const float* x      = (const float*)d_in[0];
    const float* W1     = (const float*)d_in[1];
    const float* b1     = (const float*)d_in[2];
    const float* tau_m1 = (const float*)d_in[3];
    const float* tau_n1 = (const float*)d_in[4];
    const float* W2     = (const float*)d_in[5];
    const float* b2     = (const float*)d_in[6];
    const float* tau_m2 = (const float*)d_in[7];
    const float* tau_n2 = (const float*)d_in[8];
    const float* Wx     = (const float*)d_in[9];
    const float* bx     = (const float*)d_in[10];
    const float* Wm     = (const float*)d_in[11];
    const float* bm     = (const float*)d_in[12];
    const float* Wa     = (const float*)d_in[13];
    const float* ba     = (const float*)d_in[14];
    const float* Wd     = (const float*)d_in[15];
    const float* bd     = (const float*)d_in[16];
    const float* tau_md = (const float*)d_in[17];
    float* out  = (float*)d_out;
    float* w2pk = (float*)d_ws;                       // 400*40   = 16000 floats
    float* wxpk = (float*)d_ws + 16000;               // 2*200*64 = 25600 floats

    pack_w2<<<(400 * 40 + 255) / 256, 256, 0, stream>>>(W2, w2pk);
    pack_wx<<<(2 * 200 * 64 + 255) / 256, 256, 0, stream>>>(Wx, wxpk);

    const int batch = in_sizes[0] / (SEQ * IND);      // 256
    dhsnn_fwd<<<batch, 512, 0, stream>>>(x, W1, b1, tau_m1, tau_n1,
                                         b2, tau_m2, tau_n2,
                                         bx, bm, ba, Wm, Wa,
                                         Wd, bd, tau_md,
                                         w2pk, wxpk, out);
}